// Round 5
// baseline (209.751 us; speedup 1.0000x reference)
//
#include <hip/hip_runtime.h>
#include <math.h>

#define NSEG 4096
#define HDIM 256
#define SPB  8    // segments per MLP block -> 512 blocks = 2 blocks/CU

typedef float f32x4 __attribute__((ext_vector_type(4)));
typedef int   i32x4 __attribute__((ext_vector_type(4)));

__device__ __forceinline__ float gelu_exact(float z) {
    return 0.5f * z * (1.0f + erff(z * 0.7071067811865476f));
}

// ---------- kernel 1: parallel boundary scan -> offs[0..NSEG] ----------
// offs[b] = lower_bound(batch, b). Thread t covers batch[4t..4t+3]; emits
// offs entries where the (sorted) values change. One streaming 4MB read,
// no dependent-latency binary-search chains.
__global__ __launch_bounds__(256)
void seg_offsets_kernel(const int* __restrict__ batch, int* __restrict__ offs, int N) {
    const int t = blockIdx.x * 256 + threadIdx.x;       // t < N/4
    const int j = t * 4;
    if (j >= N) return;
    const i32x4 v = __builtin_nontemporal_load(reinterpret_cast<const i32x4*>(batch + j));
    const int prev = (t == 0) ? -1 : batch[j - 1];
    int a = prev;
    #pragma unroll
    for (int u = 0; u < 4; ++u) {
        const int b_ = v[u];
        for (int b = a + 1; b <= b_; ++b) offs[b] = j + u;
        a = b_;
    }
    if (j + 3 == N - 1) {
        for (int b = a + 1; b <= NSEG; ++b) offs[b] = N;
    }
}

// ---------- kernel 2: pooled[s][:] = mean of x rows [offs[s], offs[s+1]) ----------
// One block/segment, 4 waves; wave w owns rows r0+w, r0+w+4, ...
// 8-deep unroll => 8 x 16B loads in flight per lane; nontemporal stream.
__global__ __launch_bounds__(256)
void pool_kernel(const float* __restrict__ x, const int* __restrict__ offs,
                 float* __restrict__ pooled) {
    const int s    = blockIdx.x;
    const int tid  = threadIdx.x;
    const int wave = tid >> 6;
    const int lane = tid & 63;
    const int r0 = offs[s], r1 = offs[s + 1];
    const float* colp = x + (size_t)lane * 4;

    f32x4 acc[8];
    #pragma unroll
    for (int u = 0; u < 8; ++u) acc[u] = (f32x4)(0.f);

    int r = r0 + wave;
    for (; r + 28 < r1; r += 32) {
        #pragma unroll
        for (int u = 0; u < 8; ++u) {
            const f32x4 v = __builtin_nontemporal_load(
                reinterpret_cast<const f32x4*>(colp + (size_t)(r + 4 * u) * HDIM));
            acc[u] += v;
        }
    }
    for (; r < r1; r += 4) {
        const f32x4 v = __builtin_nontemporal_load(
            reinterpret_cast<const f32x4*>(colp + (size_t)r * HDIM));
        acc[0] += v;
    }
    #pragma unroll
    for (int u = 0; u < 4; ++u) acc[u] += acc[u + 4];
    acc[0] += acc[2];
    acc[1] += acc[3];
    acc[0] += acc[1];

    __shared__ float part[4][HDIM];
    *reinterpret_cast<f32x4*>(&part[wave][lane * 4]) = acc[0];
    __syncthreads();
    float sum = (part[0][tid] + part[1][tid]) + (part[2][tid] + part[3][tid]);
    const int cnt = r1 - r0;
    pooled[(size_t)s * HDIM + tid] = sum / (float)(cnt > 1 ? cnt : 1);
}

// ---------- kernel 3: out = gelu(P @ W1 + b1) @ W2 + b2, 8 segments/block ----------
// 512 blocks = 2/CU (2 waves/SIMD -> latency hiding for L2 weight loads).
// Wave -> 2 rows, lane -> 4 cols, acc[2][4] register tile.
__global__ __launch_bounds__(256)
void mlp_kernel(const float* __restrict__ pooled,
                const float* __restrict__ W1, const float* __restrict__ b1,
                const float* __restrict__ W2, const float* __restrict__ b2,
                float* __restrict__ out) {
    const int s0   = blockIdx.x * SPB;
    const int tid  = threadIdx.x;
    const int row0 = (tid >> 6) * 2;   // wave -> 2 rows
    const int col0 = (tid & 63) * 4;   // lane -> 4 cols

    __shared__ float P[SPB][HDIM];
    __shared__ float Hs[SPB][HDIM];

    #pragma unroll
    for (int i = 0; i < SPB; ++i)
        P[i][tid] = pooled[(size_t)(s0 + i) * HDIM + tid];
    __syncthreads();

    // ---- layer 1
    float acc[2][4];
    #pragma unroll
    for (int i = 0; i < 2; ++i)
        #pragma unroll
        for (int j = 0; j < 4; ++j) acc[i][j] = 0.f;

    for (int k = 0; k < HDIM; k += 4) {
        const float4 w0 = *(const float4*)(W1 + (size_t)(k + 0) * HDIM + col0);
        const float4 w1 = *(const float4*)(W1 + (size_t)(k + 1) * HDIM + col0);
        const float4 w2 = *(const float4*)(W1 + (size_t)(k + 2) * HDIM + col0);
        const float4 w3 = *(const float4*)(W1 + (size_t)(k + 3) * HDIM + col0);
        #pragma unroll
        for (int i = 0; i < 2; ++i) {
            const float4 p = *(const float4*)(&P[row0 + i][k]);   // wave-broadcast
            acc[i][0] = fmaf(p.x, w0.x, acc[i][0]); acc[i][1] = fmaf(p.x, w0.y, acc[i][1]);
            acc[i][2] = fmaf(p.x, w0.z, acc[i][2]); acc[i][3] = fmaf(p.x, w0.w, acc[i][3]);
            acc[i][0] = fmaf(p.y, w1.x, acc[i][0]); acc[i][1] = fmaf(p.y, w1.y, acc[i][1]);
            acc[i][2] = fmaf(p.y, w1.z, acc[i][2]); acc[i][3] = fmaf(p.y, w1.w, acc[i][3]);
            acc[i][0] = fmaf(p.z, w2.x, acc[i][0]); acc[i][1] = fmaf(p.z, w2.y, acc[i][1]);
            acc[i][2] = fmaf(p.z, w2.z, acc[i][2]); acc[i][3] = fmaf(p.z, w2.w, acc[i][3]);
            acc[i][0] = fmaf(p.w, w3.x, acc[i][0]); acc[i][1] = fmaf(p.w, w3.y, acc[i][1]);
            acc[i][2] = fmaf(p.w, w3.z, acc[i][2]); acc[i][3] = fmaf(p.w, w3.w, acc[i][3]);
        }
    }
    {
        const float4 bb = *(const float4*)(b1 + col0);
        const float bv[4] = {bb.x, bb.y, bb.z, bb.w};
        #pragma unroll
        for (int i = 0; i < 2; ++i) {
            float4 h;
            h.x = gelu_exact(acc[i][0] + bv[0]);
            h.y = gelu_exact(acc[i][1] + bv[1]);
            h.z = gelu_exact(acc[i][2] + bv[2]);
            h.w = gelu_exact(acc[i][3] + bv[3]);
            *(float4*)&Hs[row0 + i][col0] = h;
        }
    }
    __syncthreads();

    // ---- layer 2
    #pragma unroll
    for (int i = 0; i < 2; ++i)
        #pragma unroll
        for (int j = 0; j < 4; ++j) acc[i][j] = 0.f;

    for (int k = 0; k < HDIM; k += 4) {
        const float4 w0 = *(const float4*)(W2 + (size_t)(k + 0) * HDIM + col0);
        const float4 w1 = *(const float4*)(W2 + (size_t)(k + 1) * HDIM + col0);
        const float4 w2 = *(const float4*)(W2 + (size_t)(k + 2) * HDIM + col0);
        const float4 w3 = *(const float4*)(W2 + (size_t)(k + 3) * HDIM + col0);
        #pragma unroll
        for (int i = 0; i < 2; ++i) {
            const float4 p = *(const float4*)(&Hs[row0 + i][k]);
            acc[i][0] = fmaf(p.x, w0.x, acc[i][0]); acc[i][1] = fmaf(p.x, w0.y, acc[i][1]);
            acc[i][2] = fmaf(p.x, w0.z, acc[i][2]); acc[i][3] = fmaf(p.x, w0.w, acc[i][3]);
            acc[i][0] = fmaf(p.y, w1.x, acc[i][0]); acc[i][1] = fmaf(p.y, w1.y, acc[i][1]);
            acc[i][2] = fmaf(p.y, w1.z, acc[i][2]); acc[i][3] = fmaf(p.y, w1.w, acc[i][3]);
            acc[i][0] = fmaf(p.z, w2.x, acc[i][0]); acc[i][1] = fmaf(p.z, w2.y, acc[i][1]);
            acc[i][2] = fmaf(p.z, w2.z, acc[i][2]); acc[i][3] = fmaf(p.z, w2.w, acc[i][3]);
            acc[i][0] = fmaf(p.w, w3.x, acc[i][0]); acc[i][1] = fmaf(p.w, w3.y, acc[i][1]);
            acc[i][2] = fmaf(p.w, w3.z, acc[i][2]); acc[i][3] = fmaf(p.w, w3.w, acc[i][3]);
        }
    }
    {
        const float4 bb = *(const float4*)(b2 + col0);
        #pragma unroll
        for (int i = 0; i < 2; ++i) {
            f32x4 o;
            o.x = acc[i][0] + bb.x;
            o.y = acc[i][1] + bb.y;
            o.z = acc[i][2] + bb.z;
            o.w = acc[i][3] + bb.w;
            __builtin_nontemporal_store(o,
                reinterpret_cast<f32x4*>(out + (size_t)(s0 + row0 + i) * HDIM + col0));
        }
    }
}

// ---------- fallback: fused kernel (used only if ws too small) ----------
__global__ __launch_bounds__(256)
void fused_pool_mlp(const float* __restrict__ x, const int* __restrict__ batch,
                    const float* __restrict__ W1, const float* __restrict__ b1,
                    const float* __restrict__ W2, const float* __restrict__ b2,
                    float* __restrict__ out, int N)
{
    const int s = blockIdx.x, tid = threadIdx.x;
    const int wave = tid >> 6, lane = tid & 63;
    __shared__ int s_r0, s_r1;
    if (tid == 0) {
        int lo = 0, hi = N;
        while (lo < hi) { int m = (lo + hi) >> 1; if (batch[m] < s)     lo = m + 1; else hi = m; }
        s_r0 = lo; hi = N;
        while (lo < hi) { int m = (lo + hi) >> 1; if (batch[m] < s + 1) lo = m + 1; else hi = m; }
        s_r1 = lo;
    }
    __syncthreads();
    const int r0 = s_r0, r1 = s_r1;
    float4 a0 = make_float4(0.f,0.f,0.f,0.f), a1 = a0;
    int r = r0 + wave;
    for (; r + 4 < r1; r += 8) {
        const float4 v0 = *(const float4*)(x + (size_t)r       * HDIM + lane * 4);
        const float4 v1 = *(const float4*)(x + (size_t)(r + 4) * HDIM + lane * 4);
        a0.x += v0.x; a0.y += v0.y; a0.z += v0.z; a0.w += v0.w;
        a1.x += v1.x; a1.y += v1.y; a1.z += v1.z; a1.w += v1.w;
    }
    if (r < r1) {
        const float4 v0 = *(const float4*)(x + (size_t)r * HDIM + lane * 4);
        a0.x += v0.x; a0.y += v0.y; a0.z += v0.z; a0.w += v0.w;
    }
    a0.x += a1.x; a0.y += a1.y; a0.z += a1.z; a0.w += a1.w;
    __shared__ float4 part4[4][64];
    __shared__ float pooled[HDIM];
    __shared__ float hbuf[HDIM];
    part4[wave][lane] = a0;
    __syncthreads();
    const float* pf = (const float*)part4;
    float sum = (pf[tid] + pf[256 + tid]) + (pf[512 + tid] + pf[768 + tid]);
    const int cnt = r1 - r0;
    pooled[tid] = sum / (float)(cnt > 1 ? cnt : 1);
    __syncthreads();
    float c0 = 0.f, c1 = 0.f, c2 = 0.f, c3 = 0.f;
    for (int k = 0; k < HDIM; k += 4) {
        c0 = fmaf(pooled[k + 0], W1[(k + 0) * HDIM + tid], c0);
        c1 = fmaf(pooled[k + 1], W1[(k + 1) * HDIM + tid], c1);
        c2 = fmaf(pooled[k + 2], W1[(k + 2) * HDIM + tid], c2);
        c3 = fmaf(pooled[k + 3], W1[(k + 3) * HDIM + tid], c3);
    }
    const float z = (c0 + c1) + (c2 + c3) + b1[tid];
    hbuf[tid] = gelu_exact(z);
    __syncthreads();
    c0 = c1 = c2 = c3 = 0.f;
    for (int k = 0; k < HDIM; k += 4) {
        c0 = fmaf(hbuf[k + 0], W2[(k + 0) * HDIM + tid], c0);
        c1 = fmaf(hbuf[k + 1], W2[(k + 1) * HDIM + tid], c1);
        c2 = fmaf(hbuf[k + 2], W2[(k + 2) * HDIM + tid], c2);
        c3 = fmaf(hbuf[k + 3], W2[(k + 3) * HDIM + tid], c3);
    }
    out[(size_t)s * HDIM + tid] = (c0 + c1) + (c2 + c3) + b2[tid];
}

extern "C" void kernel_launch(void* const* d_in, const int* in_sizes, int n_in,
                              void* d_out, int out_size, void* d_ws, size_t ws_size,
                              hipStream_t stream) {
    // setup_inputs order: x, edge_index, edge_type, batch, W1, b1, W2, b2
    const float* x     = (const float*)d_in[0];
    const int*   batch = (const int*)  d_in[3];
    const float* W1    = (const float*)d_in[4];
    const float* b1    = (const float*)d_in[5];
    const float* W2    = (const float*)d_in[6];
    const float* b2    = (const float*)d_in[7];
    float* out = (float*)d_out;
    const int N = in_sizes[3];   // 1048576 rows

    const size_t pooled_bytes = (size_t)NSEG * HDIM * sizeof(float);
    const size_t offs_bytes   = (size_t)(NSEG + 1) * sizeof(int);

    if (ws_size >= pooled_bytes + offs_bytes && (N & 3) == 0) {
        float* pooled = (float*)d_ws;
        int*   offs   = (int*)((char*)d_ws + pooled_bytes);
        hipLaunchKernelGGL(seg_offsets_kernel, dim3(N / 4 / 256), dim3(256), 0, stream,
                           batch, offs, N);
        hipLaunchKernelGGL(pool_kernel, dim3(NSEG), dim3(256), 0, stream,
                           x, offs, pooled);
        hipLaunchKernelGGL(mlp_kernel, dim3(NSEG / SPB), dim3(256), 0, stream,
                           pooled, W1, b1, W2, b2, out);
    } else {
        hipLaunchKernelGGL(fused_pool_mlp, dim3(NSEG), dim3(256), 0, stream,
                           x, batch, W1, b1, W2, b2, out, N);
    }
}

// Round 6
// 202.019 us; speedup vs baseline: 1.0383x; 1.0383x over previous
//
#include <hip/hip_runtime.h>
#include <math.h>

#define NSEG 4096
#define HDIM 256
#define SPB  16   // segments per MLP block (round-4 proven config)

typedef float f32x4 __attribute__((ext_vector_type(4)));
typedef int   i32x4 __attribute__((ext_vector_type(4)));

__device__ __forceinline__ float gelu_exact(float z) {
    return 0.5f * z * (1.0f + erff(z * 0.7071067811865476f));
}

// ---------- kernel 1: parallel boundary scan -> offs[0..NSEG] ----------
// offs[b] = lower_bound(batch, b). Thread t covers batch[4t..4t+3].
// prev value comes from lane-1's v.w via shfl; only lane 0 of each wave
// does a scalar batch[j-1] load (4096 total). One streaming pass, no
// dependent binary-search chains.
__global__ __launch_bounds__(256)
void seg_offsets_kernel(const int* __restrict__ batch, int* __restrict__ offs, int N) {
    const int t = blockIdx.x * 256 + threadIdx.x;       // t < N/4
    const int j = t * 4;
    if (j >= N) return;
    const i32x4 v = *reinterpret_cast<const i32x4*>(batch + j);
    const int lane = threadIdx.x & 63;
    const int up = __shfl_up(v.w, 1);                   // lane-1's batch[j-1]
    int a = (lane == 0) ? ((j == 0) ? -1 : batch[j - 1]) : up;
    #pragma unroll
    for (int u = 0; u < 4; ++u) {
        const int b_ = v[u];
        for (int b = a + 1; b <= b_; ++b) offs[b] = j + u;
        a = b_;
    }
    if (j + 4 >= N) {
        for (int b = a + 1; b <= NSEG; ++b) offs[b] = N;
    }
}

// ---------- kernel 2: pooled[s][:] = mean of x rows [offs[s], offs[s+1]) ----------
// One block/segment, 4 waves; wave w owns rows r0+w, r0+w+4, ...
// 8-deep unroll => 8 x 16B loads in flight per lane; nontemporal stream.
__global__ __launch_bounds__(256)
void pool_kernel(const float* __restrict__ x, const int* __restrict__ offs,
                 float* __restrict__ pooled) {
    const int s    = blockIdx.x;
    const int tid  = threadIdx.x;
    const int wave = tid >> 6;
    const int lane = tid & 63;
    const int r0 = offs[s], r1 = offs[s + 1];
    const float* colp = x + (size_t)lane * 4;

    f32x4 acc[8];
    #pragma unroll
    for (int u = 0; u < 8; ++u) acc[u] = (f32x4)(0.f);

    int r = r0 + wave;
    for (; r + 28 < r1; r += 32) {
        #pragma unroll
        for (int u = 0; u < 8; ++u) {
            const f32x4 v = __builtin_nontemporal_load(
                reinterpret_cast<const f32x4*>(colp + (size_t)(r + 4 * u) * HDIM));
            acc[u] += v;
        }
    }
    for (; r < r1; r += 4) {
        const f32x4 v = __builtin_nontemporal_load(
            reinterpret_cast<const f32x4*>(colp + (size_t)r * HDIM));
        acc[0] += v;
    }
    #pragma unroll
    for (int u = 0; u < 4; ++u) acc[u] += acc[u + 4];
    acc[0] += acc[2];
    acc[1] += acc[3];
    acc[0] += acc[1];

    __shared__ float part[4][HDIM];
    *reinterpret_cast<f32x4*>(&part[wave][lane * 4]) = acc[0];
    __syncthreads();
    float sum = (part[0][tid] + part[1][tid]) + (part[2][tid] + part[3][tid]);
    const int cnt = r1 - r0;
    pooled[(size_t)s * HDIM + tid] = sum / (float)(cnt > 1 ? cnt : 1);
}

// ---------- kernel 3: out = gelu(P @ W1 + b1) @ W2 + b2, 16 segments/block ----------
// Round-4 proven config: 256 blocks, wave -> 4 rows, lane -> 4 cols.
__global__ __launch_bounds__(256)
void mlp_kernel(const float* __restrict__ pooled,
                const float* __restrict__ W1, const float* __restrict__ b1,
                const float* __restrict__ W2, const float* __restrict__ b2,
                float* __restrict__ out) {
    const int s0   = blockIdx.x * SPB;
    const int tid  = threadIdx.x;
    const int row0 = (tid >> 6) * 4;   // wave -> 4 rows
    const int col0 = (tid & 63) * 4;   // lane -> 4 cols

    __shared__ float P[SPB][HDIM];
    __shared__ float Hs[SPB][HDIM];

    #pragma unroll
    for (int i = 0; i < SPB; ++i)
        P[i][tid] = pooled[(size_t)(s0 + i) * HDIM + tid];
    __syncthreads();

    // ---- layer 1
    float acc[4][4];
    #pragma unroll
    for (int i = 0; i < 4; ++i)
        #pragma unroll
        for (int j = 0; j < 4; ++j) acc[i][j] = 0.f;

    for (int k = 0; k < HDIM; k += 4) {
        const float4 w0 = *(const float4*)(W1 + (size_t)(k + 0) * HDIM + col0);
        const float4 w1 = *(const float4*)(W1 + (size_t)(k + 1) * HDIM + col0);
        const float4 w2 = *(const float4*)(W1 + (size_t)(k + 2) * HDIM + col0);
        const float4 w3 = *(const float4*)(W1 + (size_t)(k + 3) * HDIM + col0);
        #pragma unroll
        for (int i = 0; i < 4; ++i) {
            const float4 p = *(const float4*)(&P[row0 + i][k]);   // wave-broadcast
            acc[i][0] = fmaf(p.x, w0.x, acc[i][0]); acc[i][1] = fmaf(p.x, w0.y, acc[i][1]);
            acc[i][2] = fmaf(p.x, w0.z, acc[i][2]); acc[i][3] = fmaf(p.x, w0.w, acc[i][3]);
            acc[i][0] = fmaf(p.y, w1.x, acc[i][0]); acc[i][1] = fmaf(p.y, w1.y, acc[i][1]);
            acc[i][2] = fmaf(p.y, w1.z, acc[i][2]); acc[i][3] = fmaf(p.y, w1.w, acc[i][3]);
            acc[i][0] = fmaf(p.z, w2.x, acc[i][0]); acc[i][1] = fmaf(p.z, w2.y, acc[i][1]);
            acc[i][2] = fmaf(p.z, w2.z, acc[i][2]); acc[i][3] = fmaf(p.z, w2.w, acc[i][3]);
            acc[i][0] = fmaf(p.w, w3.x, acc[i][0]); acc[i][1] = fmaf(p.w, w3.y, acc[i][1]);
            acc[i][2] = fmaf(p.w, w3.z, acc[i][2]); acc[i][3] = fmaf(p.w, w3.w, acc[i][3]);
        }
    }
    {
        const float4 bb = *(const float4*)(b1 + col0);
        const float bv[4] = {bb.x, bb.y, bb.z, bb.w};
        #pragma unroll
        for (int i = 0; i < 4; ++i) {
            float4 h;
            h.x = gelu_exact(acc[i][0] + bv[0]);
            h.y = gelu_exact(acc[i][1] + bv[1]);
            h.z = gelu_exact(acc[i][2] + bv[2]);
            h.w = gelu_exact(acc[i][3] + bv[3]);
            *(float4*)&Hs[row0 + i][col0] = h;
        }
    }
    __syncthreads();

    // ---- layer 2
    #pragma unroll
    for (int i = 0; i < 4; ++i)
        #pragma unroll
        for (int j = 0; j < 4; ++j) acc[i][j] = 0.f;

    for (int k = 0; k < HDIM; k += 4) {
        const float4 w0 = *(const float4*)(W2 + (size_t)(k + 0) * HDIM + col0);
        const float4 w1 = *(const float4*)(W2 + (size_t)(k + 1) * HDIM + col0);
        const float4 w2 = *(const float4*)(W2 + (size_t)(k + 2) * HDIM + col0);
        const float4 w3 = *(const float4*)(W2 + (size_t)(k + 3) * HDIM + col0);
        #pragma unroll
        for (int i = 0; i < 4; ++i) {
            const float4 p = *(const float4*)(&Hs[row0 + i][k]);
            acc[i][0] = fmaf(p.x, w0.x, acc[i][0]); acc[i][1] = fmaf(p.x, w0.y, acc[i][1]);
            acc[i][2] = fmaf(p.x, w0.z, acc[i][2]); acc[i][3] = fmaf(p.x, w0.w, acc[i][3]);
            acc[i][0] = fmaf(p.y, w1.x, acc[i][0]); acc[i][1] = fmaf(p.y, w1.y, acc[i][1]);
            acc[i][2] = fmaf(p.y, w1.z, acc[i][2]); acc[i][3] = fmaf(p.y, w1.w, acc[i][3]);
            acc[i][0] = fmaf(p.z, w2.x, acc[i][0]); acc[i][1] = fmaf(p.z, w2.y, acc[i][1]);
            acc[i][2] = fmaf(p.z, w2.z, acc[i][2]); acc[i][3] = fmaf(p.z, w2.w, acc[i][3]);
            acc[i][0] = fmaf(p.w, w3.x, acc[i][0]); acc[i][1] = fmaf(p.w, w3.y, acc[i][1]);
            acc[i][2] = fmaf(p.w, w3.z, acc[i][2]); acc[i][3] = fmaf(p.w, w3.w, acc[i][3]);
        }
    }
    {
        const float4 bb = *(const float4*)(b2 + col0);
        const float bv[4] = {bb.x, bb.y, bb.z, bb.w};
        #pragma unroll
        for (int i = 0; i < 4; ++i) {
            float4 o;
            o.x = acc[i][0] + bv[0];
            o.y = acc[i][1] + bv[1];
            o.z = acc[i][2] + bv[2];
            o.w = acc[i][3] + bv[3];
            *(float4*)(out + (size_t)(s0 + row0 + i) * HDIM + col0) = o;
        }
    }
}

// ---------- fallback: fused kernel (used only if ws too small) ----------
__global__ __launch_bounds__(256)
void fused_pool_mlp(const float* __restrict__ x, const int* __restrict__ batch,
                    const float* __restrict__ W1, const float* __restrict__ b1,
                    const float* __restrict__ W2, const float* __restrict__ b2,
                    float* __restrict__ out, int N)
{
    const int s = blockIdx.x, tid = threadIdx.x;
    const int wave = tid >> 6, lane = tid & 63;
    __shared__ int s_r0, s_r1;
    if (tid == 0) {
        int lo = 0, hi = N;
        while (lo < hi) { int m = (lo + hi) >> 1; if (batch[m] < s)     lo = m + 1; else hi = m; }
        s_r0 = lo; hi = N;
        while (lo < hi) { int m = (lo + hi) >> 1; if (batch[m] < s + 1) lo = m + 1; else hi = m; }
        s_r1 = lo;
    }
    __syncthreads();
    const int r0 = s_r0, r1 = s_r1;
    float4 a0 = make_float4(0.f,0.f,0.f,0.f), a1 = a0;
    int r = r0 + wave;
    for (; r + 4 < r1; r += 8) {
        const float4 v0 = *(const float4*)(x + (size_t)r       * HDIM + lane * 4);
        const float4 v1 = *(const float4*)(x + (size_t)(r + 4) * HDIM + lane * 4);
        a0.x += v0.x; a0.y += v0.y; a0.z += v0.z; a0.w += v0.w;
        a1.x += v1.x; a1.y += v1.y; a1.z += v1.z; a1.w += v1.w;
    }
    if (r < r1) {
        const float4 v0 = *(const float4*)(x + (size_t)r * HDIM + lane * 4);
        a0.x += v0.x; a0.y += v0.y; a0.z += v0.z; a0.w += v0.w;
    }
    a0.x += a1.x; a0.y += a1.y; a0.z += a1.z; a0.w += a1.w;
    __shared__ float4 part4[4][64];
    __shared__ float pooled[HDIM];
    __shared__ float hbuf[HDIM];
    part4[wave][lane] = a0;
    __syncthreads();
    const float* pf = (const float*)part4;
    float sum = (pf[tid] + pf[256 + tid]) + (pf[512 + tid] + pf[768 + tid]);
    const int cnt = r1 - r0;
    pooled[tid] = sum / (float)(cnt > 1 ? cnt : 1);
    __syncthreads();
    float c0 = 0.f, c1 = 0.f, c2 = 0.f, c3 = 0.f;
    for (int k = 0; k < HDIM; k += 4) {
        c0 = fmaf(pooled[k + 0], W1[(k + 0) * HDIM + tid], c0);
        c1 = fmaf(pooled[k + 1], W1[(k + 1) * HDIM + tid], c1);
        c2 = fmaf(pooled[k + 2], W1[(k + 2) * HDIM + tid], c2);
        c3 = fmaf(pooled[k + 3], W1[(k + 3) * HDIM + tid], c3);
    }
    const float z = (c0 + c1) + (c2 + c3) + b1[tid];
    hbuf[tid] = gelu_exact(z);
    __syncthreads();
    c0 = c1 = c2 = c3 = 0.f;
    for (int k = 0; k < HDIM; k += 4) {
        c0 = fmaf(hbuf[k + 0], W2[(k + 0) * HDIM + tid], c0);
        c1 = fmaf(hbuf[k + 1], W2[(k + 1) * HDIM + tid], c1);
        c2 = fmaf(hbuf[k + 2], W2[(k + 2) * HDIM + tid], c2);
        c3 = fmaf(hbuf[k + 3], W2[(k + 3) * HDIM + tid], c3);
    }
    out[(size_t)s * HDIM + tid] = (c0 + c1) + (c2 + c3) + b2[tid];
}

extern "C" void kernel_launch(void* const* d_in, const int* in_sizes, int n_in,
                              void* d_out, int out_size, void* d_ws, size_t ws_size,
                              hipStream_t stream) {
    // setup_inputs order: x, edge_index, edge_type, batch, W1, b1, W2, b2
    const float* x     = (const float*)d_in[0];
    const int*   batch = (const int*)  d_in[3];
    const float* W1    = (const float*)d_in[4];
    const float* b1    = (const float*)d_in[5];
    const float* W2    = (const float*)d_in[6];
    const float* b2    = (const float*)d_in[7];
    float* out = (float*)d_out;
    const int N = in_sizes[3];   // 1048576 rows

    const size_t pooled_bytes = (size_t)NSEG * HDIM * sizeof(float);
    const size_t offs_bytes   = (size_t)(NSEG + 1) * sizeof(int);

    if (ws_size >= pooled_bytes + offs_bytes && (N & 3) == 0) {
        float* pooled = (float*)d_ws;
        int*   offs   = (int*)((char*)d_ws + pooled_bytes);
        hipLaunchKernelGGL(seg_offsets_kernel, dim3((N / 4 + 255) / 256), dim3(256), 0, stream,
                           batch, offs, N);
        hipLaunchKernelGGL(pool_kernel, dim3(NSEG), dim3(256), 0, stream,
                           x, offs, pooled);
        hipLaunchKernelGGL(mlp_kernel, dim3(NSEG / SPB), dim3(256), 0, stream,
                           pooled, W1, b1, W2, b2, out);
    } else {
        hipLaunchKernelGGL(fused_pool_mlp, dim3(NSEG), dim3(256), 0, stream,
                           x, batch, W1, b1, W2, b2, out, N);
    }
}